// Round 7
// baseline (77.591 us; speedup 1.0000x reference)
//
#include <hip/hip_runtime.h>
#include <hip/hip_bf16.h>

typedef __attribute__((ext_vector_type(8))) short short8;
typedef __attribute__((ext_vector_type(4))) float floatx4;

#define B_SZ   64
#define N_TOK  32
#define S_TOK  1024
#define D_DIM  128
#define ALPHA  0.3f

#define STRIP_S     32
#define STRIP_EL    (STRIP_S * D_DIM)       // 4096 elements
#define STRIP_BYTES (STRIP_EL * 2)          // 8192 B
#define NSTRIP      (S_TOK / STRIP_S)       // 32
#define C_EL        (S_TOK * D_DIM)         // 131072 elements per doc batch

#define DBLK (B_SZ * S_TOK * D_DIM / 8 / 256)   // 4096 blocks for D part
#define QBLK (B_SZ * N_TOK * D_DIM / 8 / 256)   // 128 blocks for Q part

__device__ __forceinline__ short f2bf(float f) {
    __hip_bfloat16 h = __float2bfloat16(f);
    return __builtin_bit_cast(short, h);
}

__device__ __forceinline__ short8 cvt8(const float* __restrict__ p) {
    floatx4 f0 = *reinterpret_cast<const floatx4*>(p);
    floatx4 f1 = *reinterpret_cast<const floatx4*>(p + 4);
    short8 r;
    r[0] = f2bf(f0[0]); r[1] = f2bf(f0[1]); r[2] = f2bf(f0[2]); r[3] = f2bf(f0[3]);
    r[4] = f2bf(f1[0]); r[5] = f2bf(f1[1]); r[6] = f2bf(f1[2]); r[7] = f2bf(f1[3]);
    return r;
}

// One launch converts everything. grid (DBLK + QBLK, 2).
// D part: fp32 -> bf16 with fragment permutation:
//   dst pos = c*C_EL + st*STRIP_EL + (ks*2+nt)*512 + (lg*16+lr)*8
//   where s = st*32 + nt*16 + lr, k = ks*32 + lg*8.
// Q part: plain layout-preserving fp32 -> bf16.
__global__ __launch_bounds__(256) void cvt_all_kernel(
    const float* __restrict__ q,  const float* __restrict__ d,
    const float* __restrict__ tq, const float* __restrict__ td,
    __hip_bfloat16* __restrict__ qb,  __hip_bfloat16* __restrict__ db,
    __hip_bfloat16* __restrict__ tqb, __hip_bfloat16* __restrict__ tdb) {
    const int which = blockIdx.y;
    if (blockIdx.x >= DBLK) {
        const float* src = which ? tq : q;
        __hip_bfloat16* dst = which ? tqb : qb;
        int idx = (blockIdx.x - DBLK) * 256 + threadIdx.x;
        *reinterpret_cast<short8*>(dst + (size_t)idx * 8) = cvt8(src + (size_t)idx * 8);
    } else {
        const float* src = which ? td : d;
        __hip_bfloat16* dst = which ? tdb : db;
        int idx = blockIdx.x * 256 + threadIdx.x;
        int kc = idx & 15;            // k-chunk 0..15
        int s  = (idx >> 4) & (S_TOK - 1);
        int c  = idx >> 14;
        int st = s >> 5, nt = (s >> 4) & 1, lr = s & 15;
        int ks = kc >> 2, lg = kc & 3;
        size_t dpos = (size_t)c * C_EL + (size_t)st * STRIP_EL
                    + (size_t)(ks * 2 + nt) * 512 + (size_t)(lg * 16 + lr) * 8;
        *reinterpret_cast<short8*>(dst + dpos) = cvt8(src + (size_t)idx * 8);
    }
}

// Grid: (c = 64, bg = 4, which = 2) = 512 blocks (2/CU), 256 threads (4 waves).
// Wave w owns 4 batches b0 = bg*16 + w*4 .. +3 (M = 128 rows per wave).
// NO LDS, NO barriers: B fragments stream L2 -> registers, double-buffered
// at nt-phase granularity. Waves are fully independent.
__global__ __launch_bounds__(256, 2) void maxsim_scores_kernel(
    const __hip_bfloat16* __restrict__ qb,  const __hip_bfloat16* __restrict__ db,
    const __hip_bfloat16* __restrict__ tqb, const __hip_bfloat16* __restrict__ tdb,
    float* __restrict__ scores_ws /* [2][64][64] */) {

    const int c     = blockIdx.x;
    const int bg    = blockIdx.y;
    const int which = blockIdx.z;
    const __hip_bfloat16* Q = which ? tqb : qb;
    const __hip_bfloat16* D = which ? tdb : db;
    float* out = scores_ws + which * (B_SZ * B_SZ);

    const int tid = threadIdx.x;
    const int w   = tid >> 6;     // wave 0..3
    const int l   = tid & 63;     // lane
    const int lg  = l >> 4;       // k-subrange 0..3
    const int lr  = l & 15;       // row/col within 16

    const int b0 = bg * 16 + w * 4;

    // A fragments: mt 0..7 -> batch b0 + (mt>>1), row (mt&1)*16 + lr. 128 regs.
    short8 afrag[8][4];
#pragma unroll
    for (int mt = 0; mt < 8; ++mt)
#pragma unroll
        for (int ks = 0; ks < 4; ++ks)
            afrag[mt][ks] = *reinterpret_cast<const short8*>(
                Q + ((size_t)(b0 + (mt >> 1)) * N_TOK + (mt & 1) * 16 + lr) * D_DIM
                  + ks * 32 + lg * 8);
    // Keep-alive: forbid sinking the Q loads into the strip loop.
#pragma unroll
    for (int mt = 0; mt < 8; ++mt)
#pragma unroll
        for (int ks = 0; ks < 4; ++ks)
            asm volatile("" : "+v"(afrag[mt][ks]));

    float runmax[8][4];
#pragma unroll
    for (int mt = 0; mt < 8; ++mt)
#pragma unroll
        for (int j = 0; j < 4; ++j) runmax[mt][j] = -INFINITY;

    // Per-lane base pointer into the permuted D[c] slice.
    const char* gbase = (const char*)(D + (size_t)c * C_EL) + l * 16;

    // Phase (st, nt) loads 4 chunks at st*8192 + (ks*2+nt)*1024.
    auto load_phase = [&](short8 bb[4], int st, int nt) {
        const char* p = gbase + (size_t)st * STRIP_BYTES + nt * 1024;
#pragma unroll
        for (int ks = 0; ks < 4; ++ks)
            bb[ks] = *reinterpret_cast<const short8*>(p + ks * 2048);
    };

    auto compute = [&](const short8 bb[4]) {
        floatx4 acc[8];
#pragma unroll
        for (int mt = 0; mt < 8; ++mt) acc[mt] = floatx4{0.f, 0.f, 0.f, 0.f};
#pragma unroll
        for (int ks = 0; ks < 4; ++ks)
#pragma unroll
            for (int mt = 0; mt < 8; ++mt)
                acc[mt] = __builtin_amdgcn_mfma_f32_16x16x32_bf16(
                    afrag[mt][ks], bb[ks], acc[mt], 0, 0, 0);
#pragma unroll
        for (int mt = 0; mt < 8; ++mt)
#pragma unroll
            for (int j = 0; j < 4; ++j)
                runmax[mt][j] = fmaxf(runmax[mt][j], acc[mt][j]);
    };

    short8 bb0[4], bb1[4];
    load_phase(bb0, 0, 0);                 // prologue

    for (int st = 0; st < NSTRIP - 1; ++st) {
        load_phase(bb1, st, 1);            // issue nt=1 loads
        compute(bb0);                      // compute nt=0
        load_phase(bb0, st + 1, 0);        // issue next strip's nt=0
        compute(bb1);                      // compute nt=1
    }
    load_phase(bb1, NSTRIP - 1, 1);
    compute(bb0);
    compute(bb1);

    // Max over the 16 s-columns spread across lr.
#pragma unroll
    for (int mt = 0; mt < 8; ++mt)
#pragma unroll
        for (int j = 0; j < 4; ++j) {
            float v = runmax[mt][j];
            v = fmaxf(v, __shfl_xor(v, 1));
            v = fmaxf(v, __shfl_xor(v, 2));
            v = fmaxf(v, __shfl_xor(v, 4));
            v = fmaxf(v, __shfl_xor(v, 8));
            runmax[mt][j] = v;
        }

    // Per-batch row sums: batch b0+p covers mt = 2p, 2p+1 (rows lg*4+j).
#pragma unroll
    for (int p = 0; p < 4; ++p) {
        float s = 0.f;
#pragma unroll
        for (int j = 0; j < 4; ++j) s += runmax[2 * p][j] + runmax[2 * p + 1][j];
        s += __shfl_xor(s, 16);
        s += __shfl_xor(s, 32);
        if (l == 0) out[(b0 + p) * B_SZ + c] = s;
    }
}

// 1 block, 64 threads: final loss.
__global__ void loss_kernel(const float* __restrict__ scores_ws, float* __restrict__ out) {
    const float* sc = scores_ws;                 // student [64][64]
    const float* tc = scores_ws + B_SZ * B_SZ;   // teacher [64][64]
    const int b = threadIdx.x;                   // 0..63

    float pos = sc[b * B_SZ + b];
    float neg = -INFINITY;
    float msesum = 0.f;
#pragma unroll 8
    for (int cc = 0; cc < B_SZ; ++cc) {
        float s = sc[b * B_SZ + cc];
        float t = tc[b * B_SZ + cc];
        if (cc != b) neg = fmaxf(neg, s);
        _Float16 d16 = (_Float16)s - (_Float16)t;  // fp16 subtract (matches ref cast)
        _Float16 sq  = d16 * d16;                  // fp16 square
        msesum += (float)sq;                       // fp32 accumulation
    }
    float x = neg - pos;
    float sp = (x > 0.f) ? (x + log1pf(expf(-x))) : log1pf(expf(x));

#pragma unroll
    for (int m = 1; m < 64; m <<= 1) {
        sp     += __shfl_xor(sp, m);
        msesum += __shfl_xor(msesum, m);
    }
    if (b == 0) {
        float mse = msesum / 4096.f;
        mse = (float)(_Float16)mse;  // jnp.mean returns f16, then astype(f32)
        out[0] = sp / 64.f + ALPHA * mse;
    }
}

extern "C" void kernel_launch(void* const* d_in, const int* in_sizes, int n_in,
                              void* d_out, int out_size, void* d_ws, size_t ws_size,
                              hipStream_t stream) {
    const float* q  = (const float*)d_in[0];
    const float* d  = (const float*)d_in[1];
    const float* tq = (const float*)d_in[2];
    const float* td = (const float*)d_in[3];
    float* out = (float*)d_out;

    const size_t QN = (size_t)B_SZ * N_TOK * D_DIM;   // 262144
    const size_t DN = (size_t)B_SZ * S_TOK * D_DIM;   // 8388608

    float* scores_ws = (float*)d_ws;                                  // 32 KB
    __hip_bfloat16* qb  = (__hip_bfloat16*)((char*)d_ws + 32768);
    __hip_bfloat16* tqb = qb + QN;
    __hip_bfloat16* db  = tqb + QN;
    __hip_bfloat16* tdb = db + DN;

    cvt_all_kernel<<<dim3(DBLK + QBLK, 2), 256, 0, stream>>>(
        q, d, tq, td, qb, db, tqb, tdb);

    dim3 grid(B_SZ, B_SZ / 16, 2);
    maxsim_scores_kernel<<<grid, 256, 0, stream>>>(qb, db, tqb, tdb, scores_ws);
    loss_kernel<<<1, 64, 0, stream>>>(scores_ws, out);
}